// Round 11
// baseline (29276.324 us; speedup 1.0000x reference)
//
#include <hip/hip_runtime.h>
#include <stdint.h>

// ---------------------------------------------------------------------------
// AnmNetwork: ADMM-like complex PSD iteration. B=64, m=l=64, n=128, K=10.
//  * Sita = V relu(w + minv[rank]) V^H  (second eigh mathematically redundant)
//  * Lamda_new = (1 - eta/rho) Lamda + eta * V diag(relu(w+m)-w) V^H
//  * Output depends only on state entering iteration K-1 -> 9 eigh rounds.
//  * PRNG: JAX threefry2x32 partitionable counters (bit-exact, R5).
// R11 (round is LDS-ISSUE bound: 173 b32-pipe inst/thread ~= 2.85us measured):
//  * A in LDS as AoS float2 -> b64 ds ops: R traffic 128 -> 64 inst/thread.
//  * All-wave redundant params (lane ln computes pair ln; identical fp32 ops
//    -> identical values) + __shfl broadcast of the 8 wave-uniform i-params.
//    Removes the serialized wave-0 phase and ~45 LDS param reads/thread.
//  * combined_kernel grid unchanged: blocks 0-63 jacobi, 64-191 replay s-1.
// State (Theta/Lamda), PRNG, u, writeout stay fp64. SWEEPS=7 (absmax 0.084).
// ---------------------------------------------------------------------------

#define BATCH 64
#define MDIM 64
#define LDIM 64
#define NDIM 128
#define NSQ (NDIM * NDIM)
#define KITER 10
#define SWEEPS 7
#define RS 129                                  // LDS row stride (float2 units)
#define JAC_LDS_BYTES (NDIM * RS * (int)sizeof(float2))      // 132,096 B
#define RCH 9                                   // replay chunk col stride
#define OUT_ELEMS 266240   // 64*64*64 (T) + 64*64 (uvec), f32 real parts

// ----------------------------- threefry2x32 --------------------------------
__device__ __forceinline__ void tf_block(unsigned k0, unsigned k1,
                                         unsigned& x0, unsigned& x1) {
  unsigned k2 = k0 ^ k1 ^ 0x1BD11BDAu;
  x0 += k0; x1 += k1;
#define TF_R(r) { x0 += x1; x1 = (x1 << (r)) | (x1 >> (32 - (r))); x1 ^= x0; }
  TF_R(13) TF_R(15) TF_R(26) TF_R(6)
  x0 += k1; x1 += k2 + 1u;
  TF_R(17) TF_R(29) TF_R(16) TF_R(24)
  x0 += k2; x1 += k0 + 2u;
  TF_R(13) TF_R(15) TF_R(26) TF_R(6)
  x0 += k0; x1 += k1 + 3u;
  TF_R(17) TF_R(29) TF_R(16) TF_R(24)
  x0 += k1; x1 += k2 + 4u;
  TF_R(13) TF_R(15) TF_R(26) TF_R(6)
  x0 += k2; x1 += k0 + 5u;
#undef TF_R
}

// ------------------------------- erfinv (f64) ------------------------------
__device__ double erfinv_d(double x) {
  double w = -log1p(-x * x);
  double p;
  if (w < 6.25) {
    w -= 3.125;
    const double c[23] = {
      -3.6444120640178196996e-21, -1.685059138182016589e-19,
      1.2858480715256400167e-18,  1.115787767802518096e-17,
      -1.333171662854620906e-16,  2.0972767875968561637e-17,
      6.6376381343583238325e-15,  -4.0545662729752068639e-14,
      -8.1519341976054721522e-14, 2.6335093153082322977e-12,
      -1.2975133253453532498e-11, -5.4154120542946279317e-11,
      1.051212273321532285e-09,   -4.1126339803469836976e-09,
      -2.9070369957882005086e-08, 4.2347877827932403518e-07,
      -1.3654692000834678645e-06, -1.3882523362786468719e-05,
      1.8673420803405714802e-04,  -7.4070253416626697512e-04,
      -6.0336708714301490533e-03, 2.4015818242558961693e-01,
      1.6536545626831027356e+00};
    p = c[0];
#pragma unroll
    for (int i = 1; i < 23; ++i) p = p * w + c[i];
  } else if (w < 16.0) {
    double s = sqrt(w) - 3.25;
    const double c[19] = {
      2.2137376921775787049e-09,  9.0756561938885390979e-08,
      -2.7517406297064545428e-07, 1.8239629214389227755e-08,
      1.5027403968909827627e-06,  -4.013867526981545969e-06,
      2.9234449089955446044e-06,  1.2475304481671778723e-05,
      -4.7318229009055733981e-05, 6.8284851459573175448e-05,
      2.4031110387097893999e-05,  -3.5503752036284748449e-04,
      9.5328937973738049703e-04,  -1.6882755560235047313e-03,
      2.4914420961078508066e-03,  -3.7512085075692412107e-03,
      5.3709145535900636051e-03,  1.0052589676941592334e+00,
      3.0838856104922207635e+00};
    p = c[0];
#pragma unroll
    for (int i = 1; i < 19; ++i) p = p * s + c[i];
  } else {
    double s = sqrt(w) - 5.0;
    const double c[17] = {
      -2.7109920616438573243e-11, -2.5556418169965252055e-10,
      1.5076572693500548083e-09,  -3.7894654401267369937e-09,
      7.6157012080783393804e-09,  -1.4960026627149240478e-08,
      2.9147953450901080826e-08,  -6.7711997758452339498e-08,
      2.2900482228026654717e-07,  -9.9298272942317002539e-07,
      4.5260625972231537039e-06,  -1.9681778105531670567e-05,
      7.5995277030017761139e-05,  -2.1503011930044477347e-04,
      -1.3871931833623122026e-04, 1.0103004648645343977e+00,
      4.8499064014085844221e+00};
    p = c[0];
#pragma unroll
    for (int i = 1; i < 17; ++i) p = p * s + c[i];
  }
  double z = p * x;
  const double spi2 = 0.8862269254527580;  // sqrt(pi)/2
  double ax = fabs(x);
#pragma unroll
  for (int nr = 0; nr < 2; ++nr) {
    if (ax > 0.9375) {
      double az = fabs(z);
      double corr = (erfc(az) - (1.0 - ax)) * spi2 * exp(az * az);
      az += corr;
      z = copysign(az, x);
    } else {
      z -= (erf(z) - x) * spi2 * exp(z * z);
    }
  }
  return z;
}

// ------------------------------- kernels -----------------------------------
__global__ void zero_kernel(double* p, size_t n) {
  size_t i = (size_t)blockIdx.x * blockDim.x + threadIdx.x;
  size_t stride = (size_t)gridDim.x * blockDim.x;
  for (; i < n; i += stride) p[i] = 0.0;
}

__global__ void prng_kernel(double* minv) {
  int tid = blockIdx.x * blockDim.x + threadIdx.x;
  if (tid >= KITER * BATCH * NDIM) return;
  int it = tid / (BATCH * NDIM);
  int i = tid % (BATCH * NDIM);
  unsigned nk0 = 0u, nk1 = (unsigned)it;
  tf_block(0u, 42u, nk0, nk1);                       // fold_in
  unsigned c0 = 0u, c1 = (unsigned)i;                // partitionable counter
  tf_block(nk0, nk1, c0, c1);
  unsigned long long bits = ((unsigned long long)c0 << 32) | (unsigned long long)c1;
  unsigned long long fb = (bits >> 12) | 0x3FF0000000000000ull;
  double f = __builtin_bit_cast(double, fb) - 1.0;
  const double lo = __builtin_bit_cast(double, 0xBFEFFFFFFFFFFFFFull);
  double uu = f * 2.0 + lo;
  if (uu < lo) uu = lo;
  minv[tid] = 1.4142135623730951 * erfinv_d(uu);
}

__global__ void compute_u_kernel(const double2* Theta, const double2* Lamda,
                                 const float* rho, const float* tau, int it,
                                 double2* u) {
  int tid = blockIdx.x * blockDim.x + threadIdx.x;
  if (tid >= BATCH * MDIM) return;
  int b = tid / MDIM, kk = tid % MDIM;
  double r = (double)rho[it], t = (double)tau[it];
  const double2* Lb = Lamda + (size_t)b * NSQ;
  const double2* Tb = Theta + (size_t)b * NSQ;
  double ar = 0.0, ai = 0.0;
  for (int i = 0; i + kk < MDIM; ++i) {
    double2 L = Lb[i * NDIM + i + kk];
    double2 Th = Tb[i * NDIM + i + kk];
    ar += L.x + r * Th.x;
    ai += L.y + r * Th.y;
  }
  if (kk == 0) ar += -(t * 0.5) * (double)MDIM;
  double s = 1.0 / ((double)(MDIM - kk) * r);
  u[b * MDIM + kk] = make_double2(ar * s, ai * s);
}

// A32 = fp32(StackM - Lamda/r) ; U32 = I
__global__ void assemble_kernel(const double2* Theta, const double2* Lamda,
                                const double2* u, const float* Yre, const float* Yim,
                                const float* rho, const float* tau, int it,
                                float2* A32, float2* U32) {
  int tid = blockIdx.x * 256 + threadIdx.x;
  if (tid >= BATCH * NSQ) return;
  int b = tid / NSQ, rem = tid % NSQ, i = rem / NDIM, j = rem % NDIM;
  double r = (double)rho[it], t = (double)tau[it];
  size_t idx = (size_t)b * NSQ + rem;
  double2 L = Lamda[idx], Th = Theta[idx];
  double axr, axi;
  if (i < MDIM && j < MDIM) {
    int d = j - i;
    double2 uv = u[b * MDIM + (d >= 0 ? d : -d)];
    double uy = (d >= 0) ? uv.y : -uv.y;
    axr = uv.x - L.x / r;
    axi = uy - L.y / r;
  } else if (i < MDIM) {
    double yr = (double)Yre[(b * MDIM + i) * LDIM + (j - MDIM)];
    double yi = (double)Yim[(b * MDIM + i) * LDIM + (j - MDIM)];
    double inv = 1.0 / (1.0 + 2.0 * r);
    axr = (yr + 2.0 * L.x + 2.0 * r * Th.x) * inv - L.x / r;
    axi = (yi + 2.0 * L.y + 2.0 * r * Th.y) * inv - L.y / r;
  } else if (j < MDIM) {
    double yr = (double)Yre[(b * MDIM + j) * LDIM + (i - MDIM)];
    double yi = -(double)Yim[(b * MDIM + j) * LDIM + (i - MDIM)];
    double inv = 1.0 / (1.0 + 2.0 * r);
    axr = (yr + 2.0 * L.x + 2.0 * r * Th.x) * inv - L.x / r;
    axi = (yi + 2.0 * L.y + 2.0 * r * Th.y) * inv - L.y / r;
  } else {
    axr = Th.x - ((i == j) ? t / (2.0 * r) : 0.0);
    axi = Th.y;
  }
  A32[idx] = make_float2((float)axr, (float)axi);
  U32[idx] = make_float2((i == j) ? 1.0f : 0.0f, 0.0f);
}

__device__ __forceinline__ int pair_p(int j, int r) {
  return (j == 0) ? 0 : 1 + (j - 1 + r) % 127;
}
__device__ __forceinline__ int pair_q(int j, int r) {
  return 1 + (126 - j + r) % 127;
}

// Replay device body: wave-owned 128x8 U column chunk in LDS, zero barriers.
__device__ void replay_body(float* smem, float2* __restrict__ U,
                            const float2* __restrict__ params,
                            int rb, int sweep) {
  int tid = threadIdx.x, wv = tid >> 6, ln = tid & 63;
  int b = rb >> 1, half = rb & 1;
  int col0 = (half * 8 + wv) * 8;
  float* cre = smem + wv * (2 * NDIM * RCH);
  float* cim = cre + NDIM * RCH;
  float2* Ug = U + (size_t)b * NSQ;
  const float2* Pg = params + (size_t)b * (127 * 64);
  for (int e = ln; e < NDIM * 8; e += 64) {
    int row = e >> 3, c = e & 7;
    float2 v = Ug[row * NDIM + col0 + c];
    cre[row * RCH + c] = v.x;
    cim[row * RCH + c] = v.y;
  }
  for (int r0 = 0; r0 < 127; ++r0) {
    int r = (sweep & 1) ? (126 - r0) : r0;
    int p = pair_p(ln, r), q = pair_q(ln, r);
    float2 prm = Pg[r0 * 64 + ln];
    float br = prm.x, bi = prm.y;
    float cc = sqrtf(fmaxf(0.0f, 1.0f - br * br - bi * bi));
#pragma unroll
    for (int c = 0; c < 8; ++c) {
      int ip = p * RCH + c, iq = q * RCH + c;
      float upx = cre[ip], upy = cim[ip];
      float uqx = cre[iq], uqy = cim[iq];
      cre[ip] = cc * upx + (br * uqx + bi * uqy);   // U_p <- c U_p + conj(sb) U_q
      cim[ip] = cc * upy + (br * uqy - bi * uqx);
      cre[iq] = cc * uqx - (br * upx - bi * upy);   // U_q <- c U_q - sb U_p
      cim[iq] = cc * uqy - (br * upy + bi * upx);
    }
    __builtin_amdgcn_wave_barrier();
  }
  for (int e = ln; e < NDIM * 8; e += 64) {
    int row = e >> 3, c = e & 7;
    Ug[row * NDIM + col0 + c] = make_float2(cre[row * RCH + c], cim[row * RCH + c]);
  }
}

// Combined dispatch: blocks 0..63 jacobi sweep `sweep` (params -> prmW);
// blocks 64..191 replay sweep-1 from prmR onto U (idle CUs).
// Jacobi: A in LDS as AoS float2 (b64 ops); all-wave redundant params +
// __shfl broadcast; 2 barriers/round.
__global__ __launch_bounds__(512) void combined_kernel(
    float2* __restrict__ A, float2* __restrict__ U,
    float2* __restrict__ prmW, const float2* __restrict__ prmR,
    const double* __restrict__ minv, int it, int sweep, int last,
    double* __restrict__ d1, double* __restrict__ d2) {
  extern __shared__ float smem[];
  if (blockIdx.x >= BATCH) {
    if (sweep > 0) replay_body(smem, U, prmR, blockIdx.x - BATCH, sweep - 1);
    return;
  }
  float2* sA = (float2*)smem;     // 128 x 129 float2 (AoS)
  int b = blockIdx.x, tid = threadIdx.x;
  int j = tid & 63, wv = tid >> 6;
  float2* Ag = A + (size_t)b * NSQ;
  float2* Pg = prmW + (size_t)b * (127 * 64);
  for (int i = tid; i < NSQ; i += 512)
    sA[(i >> 7) * RS + (i & 127)] = Ag[i];
  __syncthreads();
  for (int r0 = 0; r0 < 127; ++r0) {
    int r = (sweep & 1) ? (126 - r0) : r0;
    int pj = pair_p(j, r), qj = pair_q(j, r);
    // PHASE 1: all reads from pre-round A (own params inputs + 8 R blocks)
    float2 dpp = sA[pj * RS + pj];
    float2 dqq = sA[qj * RS + qj];
    float2 g = sA[pj * RS + qj];
    int bp[8], bq[8];
    float2 Rb[8][4];
#pragma unroll
    for (int k = 0; k < 8; ++k) {
      int i = wv + 8 * k;                        // wave-uniform -> SALU pairs
      bp[k] = pair_p(i, r) * RS; bq[k] = pair_q(i, r) * RS;
      Rb[k][0] = sA[bp[k] + pj]; Rb[k][1] = sA[bp[k] + qj];
      Rb[k][2] = sA[bq[k] + pj]; Rb[k][3] = sA[bq[k] + qj];
    }
    // PHASE 2: own params for pair j (identical fp32 ops in every wave)
    float gr = g.x, gi = g.y;
    float ag2 = gr * gr + gi * gi;
    float cc = 1.0f, br = 0.0f, bi = 0.0f;
    if (ag2 > 1e-24f) {
      float ag = sqrtf(ag2);
      float ta = (dqq.x - dpp.x) / (2.0f * ag);
      float tt = -copysignf(1.0f, ta) / (fabsf(ta) + sqrtf(1.0f + ta * ta));
      cc = 1.0f / sqrtf(1.0f + tt * tt);
      float tcag = tt * cc / ag;
      br = gr * tcag; bi = gi * tcag;
    }
    if (tid < 64) Pg[r0 * 64 + tid] = make_float2(br, bi);
    __syncthreads();   // WAR: all phase-1 reads complete before writes
    // PHASE 3: i-params via intra-wave shuffle (lane i holds pair i's params)
    float ci[8], bri[8], bii[8];
#pragma unroll
    for (int k = 0; k < 8; ++k) {
      int i = wv + 8 * k;
      ci[k] = __shfl(cc, i); bri[k] = __shfl(br, i); bii[k] = __shfl(bi, i);
    }
    // rotate 2x2 blocks: B <- L_i * B * R_j, write back (b64 stores)
#pragma unroll
    for (int k = 0; k < 8; ++k) {
      float b00r = Rb[k][0].x, b00i = Rb[k][0].y;
      float b01r = Rb[k][1].x, b01i = Rb[k][1].y;
      float b10r = Rb[k][2].x, b10i = Rb[k][2].y;
      float b11r = Rb[k][3].x, b11i = Rb[k][3].y;
      float t00r = ci[k] * b00r + (bri[k] * b10r - bii[k] * b10i);
      float t00i = ci[k] * b00i + (bri[k] * b10i + bii[k] * b10r);
      float t01r = ci[k] * b01r + (bri[k] * b11r - bii[k] * b11i);
      float t01i = ci[k] * b01i + (bri[k] * b11i + bii[k] * b11r);
      float t10r = ci[k] * b10r - (bri[k] * b00r + bii[k] * b00i);
      float t10i = ci[k] * b10i - (bri[k] * b00i - bii[k] * b00r);
      float t11r = ci[k] * b11r - (bri[k] * b01r + bii[k] * b01i);
      float t11i = ci[k] * b11i - (bri[k] * b01i - bii[k] * b01r);
      float cj = cc, brj = br, bij = bi;
      sA[bp[k] + pj] = make_float2(cj * t00r + (brj * t01r + bij * t01i),
                                   cj * t00i + (brj * t01i - bij * t01r));
      sA[bp[k] + qj] = make_float2(cj * t01r - (brj * t00r - bij * t00i),
                                   cj * t01i - (brj * t00i + bij * t00r));
      sA[bq[k] + pj] = make_float2(cj * t10r + (brj * t11r + bij * t11i),
                                   cj * t10i + (brj * t11i - bij * t11r));
      sA[bq[k] + qj] = make_float2(cj * t11r - (brj * t10r - bij * t10i),
                                   cj * t11i - (brj * t10i + bij * t10r));
    }
    __syncthreads();   // RAW: writes visible before next round's reads
  }
  for (int i = tid; i < NSQ; i += 512)
    Ag[i] = sA[(i >> 7) * RS + (i & 127)];
  if (last && tid < NDIM) {   // fused rankd
    float wj = sA[tid * RS + tid].x;
    int rank = 0;
    for (int k2 = 0; k2 < NDIM; ++k2) {
      float wk = sA[k2 * RS + k2].x;
      rank += (wk < wj) || (wk == wj && k2 < tid);
    }
    double mv = minv[(it * BATCH + b) * NDIM + rank];
    double v = (double)wj + mv;
    if (v < 0.0) v = 0.0;
    d1[b * NDIM + tid] = v;
    d2[b * NDIM + tid] = v - (double)wj;
  }
}

// Final replay of the last sweep (before update_kernel).
__global__ __launch_bounds__(512) void replay_kernel(
    float2* __restrict__ U, const float2* __restrict__ params, int sweep) {
  extern __shared__ float smem[];
  replay_body(smem, U, params, blockIdx.x, sweep);
}

// Theta = V diag(d1) V^H ; Lamda = (1-e/r) Lamda + e * V diag(d2) V^H.
__global__ __launch_bounds__(256) void update_kernel(
    const float2* U, const double* d1, const double* d2,
    const float* rho, const float* eta, int it,
    double2* Theta, double2* Lamda) {
  __shared__ float ViRe[32][33], ViIm[32][33];
  __shared__ float VkRe[32][33], VkIm[32][33];
  __shared__ double s1[32], s2[32];
  int blk = blockIdx.x;
  int b = blk >> 4, tile = blk & 15, ti = tile >> 2, tk = tile & 3;
  int tid = threadIdx.x;
  int lk = tid & 31, lig = tid >> 5;
  double r = (double)rho[it], e = (double)eta[it];
  double a1x[4] = {0, 0, 0, 0}, a1y[4] = {0, 0, 0, 0};
  double a2x[4] = {0, 0, 0, 0}, a2y[4] = {0, 0, 0, 0};
  const float2* Ub = U + (size_t)b * NSQ;
  for (int jc = 0; jc < 4; ++jc) {
    for (int e2 = tid; e2 < 1024; e2 += 256) {
      int rr = e2 & 31, cc2 = e2 >> 5;
      float2 v1 = Ub[(jc * 32 + cc2) * NDIM + ti * 32 + rr];
      ViRe[rr][cc2] = v1.x; ViIm[rr][cc2] = v1.y;
      float2 v2 = Ub[(jc * 32 + cc2) * NDIM + tk * 32 + rr];
      VkRe[rr][cc2] = v2.x; VkIm[rr][cc2] = v2.y;
    }
    if (tid < 32) {
      s1[tid] = d1[b * NDIM + jc * 32 + tid];
      s2[tid] = d2[b * NDIM + jc * 32 + tid];
    }
    __syncthreads();
#pragma unroll
    for (int uo = 0; uo < 4; ++uo) {
      int li = lig + uo * 8;
      double ax = a1x[uo], ay = a1y[uo], bx = a2x[uo], by = a2y[uo];
      for (int jj = 0; jj < 32; ++jj) {
        float var = ViRe[li][jj], vai = ViIm[li][jj];
        float vbr = VkRe[lk][jj], vbi = VkIm[lk][jj];
        double pr = (double)(var * vbr + vai * vbi);
        double pi = (double)(vai * vbr - var * vbi);
        ax += s1[jj] * pr; ay += s1[jj] * pi;
        bx += s2[jj] * pr; by += s2[jj] * pi;
      }
      a1x[uo] = ax; a1y[uo] = ay; a2x[uo] = bx; a2y[uo] = by;
    }
    __syncthreads();
  }
  double lf = 1.0 - e / r;
#pragma unroll
  for (int uo = 0; uo < 4; ++uo) {
    int gi = ti * 32 + lig + uo * 8, gk = tk * 32 + lk;
    size_t idx = (size_t)b * NSQ + gi * NDIM + gk;
    Theta[idx] = make_double2(a1x[uo], a1y[uo]);
    double2 Lold = Lamda[idx];
    Lamda[idx] = make_double2(lf * Lold.x + e * a2x[uo], lf * Lold.y + e * a2y[uo]);
  }
}

// OUTPUT (float32 real parts): T[i][j] = u[|i-j|].re ; uvec.re = u.re
__global__ void writeout_kernel(const double2* u, float* out) {
  int tid = blockIdx.x * 256 + threadIdx.x;
  if (tid >= OUT_ELEMS) return;
  double re;
  if (tid < BATCH * MDIM * MDIM) {
    int b = tid >> 12, rem = tid & 4095, i = rem >> 6, j = rem & 63;
    int d = j - i;
    re = u[b * MDIM + (d >= 0 ? d : -d)].x;
  } else {
    int k2 = tid - BATCH * MDIM * MDIM;
    int b = k2 >> 6, kk = k2 & 63;
    re = u[b * MDIM + kk].x;
  }
  out[tid] = (float)re;
}

// ------------------------------- launch ------------------------------------
extern "C" void kernel_launch(void* const* d_in, const int* in_sizes, int n_in,
                              void* d_out, int out_size, void* d_ws, size_t ws_size,
                              hipStream_t stream) {
  const float* Yre = (const float*)d_in[0];
  const float* Yim = (const float*)d_in[1];
  const float* rho = (const float*)d_in[2];
  const float* tau = (const float*)d_in[3];
  const float* eta = (const float*)d_in[4];
  float* out = (float*)d_out;

  char* ws = (char*)d_ws;
  size_t off = 0;
  auto take = [&](size_t bytes) -> char* {
    char* p = ws + off;
    off += (bytes + 255) & ~(size_t)255;
    return p;
  };
  double2* u     = (double2*)take((size_t)BATCH * MDIM * sizeof(double2));
  double*  minv  = (double*)take((size_t)KITER * BATCH * NDIM * sizeof(double));
  double*  d1    = (double*)take((size_t)BATCH * NDIM * sizeof(double));
  double*  d2    = (double*)take((size_t)BATCH * NDIM * sizeof(double));
  double2* Lamda = (double2*)take((size_t)BATCH * NSQ * sizeof(double2));  // 16.8 MB
  double2* Theta = (double2*)take((size_t)BATCH * NSQ * sizeof(double2));  // 16.8 MB
  float2*  A32   = (float2*)take((size_t)BATCH * NSQ * sizeof(float2));    //  8.4 MB
  float2*  U32   = (float2*)take((size_t)BATCH * NSQ * sizeof(float2));    //  8.4 MB
  float2*  prm0  = (float2*)take((size_t)BATCH * 127 * 64 * sizeof(float2)); // 4.2 MB
  float2*  prm1  = (float2*)take((size_t)BATCH * 127 * 64 * sizeof(float2)); // 4.2 MB
  float2*  prmB[2] = {prm0, prm1};
  (void)in_sizes; (void)n_in; (void)ws_size; (void)out_size;  // ~59.7 MB total

  hipFuncSetAttribute((const void*)combined_kernel,
                      hipFuncAttributeMaxDynamicSharedMemorySize, JAC_LDS_BYTES);
  hipFuncSetAttribute((const void*)replay_kernel,
                      hipFuncAttributeMaxDynamicSharedMemorySize, JAC_LDS_BYTES);

  zero_kernel<<<2048, 256, 0, stream>>>((double*)Theta, (size_t)BATCH * NSQ * 2);
  zero_kernel<<<2048, 256, 0, stream>>>((double*)Lamda, (size_t)BATCH * NSQ * 2);
  prng_kernel<<<(KITER * BATCH * NDIM + 255) / 256, 256, 0, stream>>>(minv);

  for (int it = 0; it < KITER - 1; ++it) {
    compute_u_kernel<<<16, 256, 0, stream>>>(Theta, Lamda, rho, tau, it, u);
    assemble_kernel<<<BATCH * NSQ / 256, 256, 0, stream>>>(Theta, Lamda, u, Yre, Yim,
                                                           rho, tau, it, A32, U32);
    for (int s = 0; s < SWEEPS; ++s) {
      combined_kernel<<<BATCH + 2 * BATCH, 512, JAC_LDS_BYTES, stream>>>(
          A32, U32, prmB[s & 1], prmB[(s + 1) & 1], minv, it, s,
          (s == SWEEPS - 1) ? 1 : 0, d1, d2);
    }
    replay_kernel<<<2 * BATCH, 512, JAC_LDS_BYTES, stream>>>(
        U32, prmB[(SWEEPS - 1) & 1], SWEEPS - 1);
    update_kernel<<<BATCH * 16, 256, 0, stream>>>(U32, d1, d2, rho, eta, it, Theta, Lamda);
  }
  compute_u_kernel<<<16, 256, 0, stream>>>(Theta, Lamda, rho, tau, KITER - 1, u);
  writeout_kernel<<<(OUT_ELEMS + 255) / 256, 256, 0, stream>>>(u, out);
}

// Round 12
// 22401.050 us; speedup vs baseline: 1.3069x; 1.3069x over previous
//
#include <hip/hip_runtime.h>
#include <stdint.h>

// ---------------------------------------------------------------------------
// AnmNetwork: ADMM-like complex PSD iteration. B=64, m=l=64, n=128, K=10.
//  * Sita = V relu(w + minv[rank]) V^H  (second eigh mathematically redundant)
//  * Lamda_new = (1 - eta/rho) Lamda + eta * V diag(relu(w+m)-w) V^H
//  * Output depends only on state entering iteration K-1 -> 9 eigh rounds.
//  * PRNG: JAX threefry2x32 partitionable counters (bit-exact, R5).
// R12 = R10 base (R11's shfl/b64 experiment regressed: __shfl = ds_bpermute
// = LDS pipe; b64 pair-scatter hits even bank pairs) + HERMITIAN HALVING:
//  * A kept canonical-upper only; rotations preserve Hermitian bit-exactly,
//    so only 2080 of 4096 slot-pair 2x2 blocks are computed (~4/thread, the
//    32 extra on wave 7; wave 0 does params). Conditional-conj accessors.
//  * params packed float4{c,br,bi,p|q<<8} in LDS -> 2 b128 reads per block.
//  * Ownership of canonical cells stays private per thread -> 2 barriers.
// State (Theta/Lamda), PRNG, u, writeout stay fp64. SWEEPS=7.
// ---------------------------------------------------------------------------

#define BATCH 64
#define MDIM 64
#define LDIM 64
#define NDIM 128
#define NSQ (NDIM * NDIM)
#define KITER 10
#define SWEEPS 7
#define RS 129                                  // LDS row stride (floats, SoA)
#define JAC_LDS_BYTES (2 * NDIM * RS * (int)sizeof(float))   // 132,096 B
#define RCH 9                                   // replay chunk col stride
#define OUT_ELEMS 266240   // 64*64*64 (T) + 64*64 (uvec), f32 real parts

// ----------------------------- threefry2x32 --------------------------------
__device__ __forceinline__ void tf_block(unsigned k0, unsigned k1,
                                         unsigned& x0, unsigned& x1) {
  unsigned k2 = k0 ^ k1 ^ 0x1BD11BDAu;
  x0 += k0; x1 += k1;
#define TF_R(r) { x0 += x1; x1 = (x1 << (r)) | (x1 >> (32 - (r))); x1 ^= x0; }
  TF_R(13) TF_R(15) TF_R(26) TF_R(6)
  x0 += k1; x1 += k2 + 1u;
  TF_R(17) TF_R(29) TF_R(16) TF_R(24)
  x0 += k2; x1 += k0 + 2u;
  TF_R(13) TF_R(15) TF_R(26) TF_R(6)
  x0 += k0; x1 += k1 + 3u;
  TF_R(17) TF_R(29) TF_R(16) TF_R(24)
  x0 += k1; x1 += k2 + 4u;
  TF_R(13) TF_R(15) TF_R(26) TF_R(6)
  x0 += k2; x1 += k0 + 5u;
#undef TF_R
}

// ------------------------------- erfinv (f64) ------------------------------
__device__ double erfinv_d(double x) {
  double w = -log1p(-x * x);
  double p;
  if (w < 6.25) {
    w -= 3.125;
    const double c[23] = {
      -3.6444120640178196996e-21, -1.685059138182016589e-19,
      1.2858480715256400167e-18,  1.115787767802518096e-17,
      -1.333171662854620906e-16,  2.0972767875968561637e-17,
      6.6376381343583238325e-15,  -4.0545662729752068639e-14,
      -8.1519341976054721522e-14, 2.6335093153082322977e-12,
      -1.2975133253453532498e-11, -5.4154120542946279317e-11,
      1.051212273321532285e-09,   -4.1126339803469836976e-09,
      -2.9070369957882005086e-08, 4.2347877827932403518e-07,
      -1.3654692000834678645e-06, -1.3882523362786468719e-05,
      1.8673420803405714802e-04,  -7.4070253416626697512e-04,
      -6.0336708714301490533e-03, 2.4015818242558961693e-01,
      1.6536545626831027356e+00};
    p = c[0];
#pragma unroll
    for (int i = 1; i < 23; ++i) p = p * w + c[i];
  } else if (w < 16.0) {
    double s = sqrt(w) - 3.25;
    const double c[19] = {
      2.2137376921775787049e-09,  9.0756561938885390979e-08,
      -2.7517406297064545428e-07, 1.8239629214389227755e-08,
      1.5027403968909827627e-06,  -4.013867526981545969e-06,
      2.9234449089955446044e-06,  1.2475304481671778723e-05,
      -4.7318229009055733981e-05, 6.8284851459573175448e-05,
      2.4031110387097893999e-05,  -3.5503752036284748449e-04,
      9.5328937973738049703e-04,  -1.6882755560235047313e-03,
      2.4914420961078508066e-03,  -3.7512085075692412107e-03,
      5.3709145535900636051e-03,  1.0052589676941592334e+00,
      3.0838856104922207635e+00};
    p = c[0];
#pragma unroll
    for (int i = 1; i < 19; ++i) p = p * s + c[i];
  } else {
    double s = sqrt(w) - 5.0;
    const double c[17] = {
      -2.7109920616438573243e-11, -2.5556418169965252055e-10,
      1.5076572693500548083e-09,  -3.7894654401267369937e-09,
      7.6157012080783393804e-09,  -1.4960026627149240478e-08,
      2.9147953450901080826e-08,  -6.7711997758452339498e-08,
      2.2900482228026654717e-07,  -9.9298272942317002539e-07,
      4.5260625972231537039e-06,  -1.9681778105531670567e-05,
      7.5995277030017761139e-05,  -2.1503011930044477347e-04,
      -1.3871931833623122026e-04, 1.0103004648645343977e+00,
      4.8499064014085844221e+00};
    p = c[0];
#pragma unroll
    for (int i = 1; i < 17; ++i) p = p * s + c[i];
  }
  double z = p * x;
  const double spi2 = 0.8862269254527580;  // sqrt(pi)/2
  double ax = fabs(x);
#pragma unroll
  for (int nr = 0; nr < 2; ++nr) {
    if (ax > 0.9375) {
      double az = fabs(z);
      double corr = (erfc(az) - (1.0 - ax)) * spi2 * exp(az * az);
      az += corr;
      z = copysign(az, x);
    } else {
      z -= (erf(z) - x) * spi2 * exp(z * z);
    }
  }
  return z;
}

// ------------------------------- kernels -----------------------------------
__global__ void zero_kernel(double* p, size_t n) {
  size_t i = (size_t)blockIdx.x * blockDim.x + threadIdx.x;
  size_t stride = (size_t)gridDim.x * blockDim.x;
  for (; i < n; i += stride) p[i] = 0.0;
}

__global__ void prng_kernel(double* minv) {
  int tid = blockIdx.x * blockDim.x + threadIdx.x;
  if (tid >= KITER * BATCH * NDIM) return;
  int it = tid / (BATCH * NDIM);
  int i = tid % (BATCH * NDIM);
  unsigned nk0 = 0u, nk1 = (unsigned)it;
  tf_block(0u, 42u, nk0, nk1);                       // fold_in
  unsigned c0 = 0u, c1 = (unsigned)i;                // partitionable counter
  tf_block(nk0, nk1, c0, c1);
  unsigned long long bits = ((unsigned long long)c0 << 32) | (unsigned long long)c1;
  unsigned long long fb = (bits >> 12) | 0x3FF0000000000000ull;
  double f = __builtin_bit_cast(double, fb) - 1.0;
  const double lo = __builtin_bit_cast(double, 0xBFEFFFFFFFFFFFFFull);
  double uu = f * 2.0 + lo;
  if (uu < lo) uu = lo;
  minv[tid] = 1.4142135623730951 * erfinv_d(uu);
}

__global__ void compute_u_kernel(const double2* Theta, const double2* Lamda,
                                 const float* rho, const float* tau, int it,
                                 double2* u) {
  int tid = blockIdx.x * blockDim.x + threadIdx.x;
  if (tid >= BATCH * MDIM) return;
  int b = tid / MDIM, kk = tid % MDIM;
  double r = (double)rho[it], t = (double)tau[it];
  const double2* Lb = Lamda + (size_t)b * NSQ;
  const double2* Tb = Theta + (size_t)b * NSQ;
  double ar = 0.0, ai = 0.0;
  for (int i = 0; i + kk < MDIM; ++i) {
    double2 L = Lb[i * NDIM + i + kk];
    double2 Th = Tb[i * NDIM + i + kk];
    ar += L.x + r * Th.x;
    ai += L.y + r * Th.y;
  }
  if (kk == 0) ar += -(t * 0.5) * (double)MDIM;
  double s = 1.0 / ((double)(MDIM - kk) * r);
  u[b * MDIM + kk] = make_double2(ar * s, ai * s);
}

// A32 = fp32(StackM - Lamda/r) ; U32 = I
__global__ void assemble_kernel(const double2* Theta, const double2* Lamda,
                                const double2* u, const float* Yre, const float* Yim,
                                const float* rho, const float* tau, int it,
                                float2* A32, float2* U32) {
  int tid = blockIdx.x * 256 + threadIdx.x;
  if (tid >= BATCH * NSQ) return;
  int b = tid / NSQ, rem = tid % NSQ, i = rem / NDIM, j = rem % NDIM;
  double r = (double)rho[it], t = (double)tau[it];
  size_t idx = (size_t)b * NSQ + rem;
  double2 L = Lamda[idx], Th = Theta[idx];
  double axr, axi;
  if (i < MDIM && j < MDIM) {
    int d = j - i;
    double2 uv = u[b * MDIM + (d >= 0 ? d : -d)];
    double uy = (d >= 0) ? uv.y : -uv.y;
    axr = uv.x - L.x / r;
    axi = uy - L.y / r;
  } else if (i < MDIM) {
    double yr = (double)Yre[(b * MDIM + i) * LDIM + (j - MDIM)];
    double yi = (double)Yim[(b * MDIM + i) * LDIM + (j - MDIM)];
    double inv = 1.0 / (1.0 + 2.0 * r);
    axr = (yr + 2.0 * L.x + 2.0 * r * Th.x) * inv - L.x / r;
    axi = (yi + 2.0 * L.y + 2.0 * r * Th.y) * inv - L.y / r;
  } else if (j < MDIM) {
    double yr = (double)Yre[(b * MDIM + j) * LDIM + (i - MDIM)];
    double yi = -(double)Yim[(b * MDIM + j) * LDIM + (i - MDIM)];
    double inv = 1.0 / (1.0 + 2.0 * r);
    axr = (yr + 2.0 * L.x + 2.0 * r * Th.x) * inv - L.x / r;
    axi = (yi + 2.0 * L.y + 2.0 * r * Th.y) * inv - L.y / r;
  } else {
    axr = Th.x - ((i == j) ? t / (2.0 * r) : 0.0);
    axi = Th.y;
  }
  A32[idx] = make_float2((float)axr, (float)axi);
  U32[idx] = make_float2((i == j) ? 1.0f : 0.0f, 0.0f);
}

__device__ __forceinline__ int pair_p(int j, int r) {
  return (j == 0) ? 0 : 1 + (j - 1 + r) % 127;
}
__device__ __forceinline__ int pair_q(int j, int r) {
  return 1 + (126 - j + r) % 127;
}

// Canonical-upper accessors (SoA planes sAre/sAim, stride RS).
__device__ __forceinline__ float2 ldc(const float* sAre, const float* sAim,
                                      int r, int c) {
  int rr = r <= c ? r : c, cc = r <= c ? c : r;
  float2 v = make_float2(sAre[rr * RS + cc], sAim[rr * RS + cc]);
  if (r > c) v.y = -v.y;
  return v;
}
__device__ __forceinline__ void stc(float* sAre, float* sAim,
                                    int r, int c, float zr, float zi) {
  int rr = r <= c ? r : c, cc = r <= c ? c : r;
  sAre[rr * RS + cc] = zr;
  sAim[rr * RS + cc] = (r <= c) ? zi : -zi;
}

// Replay device body: wave-owned 128x8 U column chunk in LDS, zero barriers.
__device__ void replay_body(float* smem, float2* __restrict__ U,
                            const float2* __restrict__ params,
                            int rb, int sweep) {
  int tid = threadIdx.x, wv = tid >> 6, ln = tid & 63;
  int b = rb >> 1, half = rb & 1;
  int col0 = (half * 8 + wv) * 8;
  float* cre = smem + wv * (2 * NDIM * RCH);
  float* cim = cre + NDIM * RCH;
  float2* Ug = U + (size_t)b * NSQ;
  const float2* Pg = params + (size_t)b * (127 * 64);
  for (int e = ln; e < NDIM * 8; e += 64) {
    int row = e >> 3, c = e & 7;
    float2 v = Ug[row * NDIM + col0 + c];
    cre[row * RCH + c] = v.x;
    cim[row * RCH + c] = v.y;
  }
  for (int r0 = 0; r0 < 127; ++r0) {
    int r = (sweep & 1) ? (126 - r0) : r0;
    int p = pair_p(ln, r), q = pair_q(ln, r);
    float2 prm = Pg[r0 * 64 + ln];
    float br = prm.x, bi = prm.y;
    float cc = sqrtf(fmaxf(0.0f, 1.0f - br * br - bi * bi));
#pragma unroll
    for (int c = 0; c < 8; ++c) {
      int ip = p * RCH + c, iq = q * RCH + c;
      float upx = cre[ip], upy = cim[ip];
      float uqx = cre[iq], uqy = cim[iq];
      cre[ip] = cc * upx + (br * uqx + bi * uqy);   // U_p <- c U_p + conj(sb) U_q
      cim[ip] = cc * upy + (br * uqy - bi * uqx);
      cre[iq] = cc * uqx - (br * upx - bi * upy);   // U_q <- c U_q - sb U_p
      cim[iq] = cc * uqy - (br * upy + bi * upx);
    }
    __builtin_amdgcn_wave_barrier();
  }
  for (int e = ln; e < NDIM * 8; e += 64) {
    int row = e >> 3, c = e & 7;
    Ug[row * NDIM + col0 + c] = make_float2(cre[row * RCH + c], cim[row * RCH + c]);
  }
}

// Combined dispatch: blocks 0..63 jacobi sweep `sweep` (params -> prmW);
// blocks 64..191 replay sweep-1 from prmR onto U (idle CUs).
// Jacobi: canonical-upper Hermitian, 2080 blocks over 512 threads
// (~4/thread, extra 32 on wave 7), params as packed float4 LDS.
__global__ __launch_bounds__(512) void combined_kernel(
    float2* __restrict__ A, float2* __restrict__ U,
    float2* __restrict__ prmW, const float2* __restrict__ prmR,
    const double* __restrict__ minv, int it, int sweep, int last,
    double* __restrict__ d1, double* __restrict__ d2) {
  extern __shared__ float smem[];
  if (blockIdx.x >= BATCH) {
    if (sweep > 0) replay_body(smem, U, prmR, blockIdx.x - BATCH, sweep - 1);
    return;
  }
  float* sAre = smem;             // 128 x 129
  float* sAim = smem + NDIM * RS;
  __shared__ float4 sprm[64];     // {c, br, bi, bitcast(p | q<<8)}
  int b = blockIdx.x, tid = threadIdx.x;
  float2* Ag = A + (size_t)b * NSQ;
  float2* Pg = prmW + (size_t)b * (127 * 64);
  for (int i = tid; i < NSQ; i += 512) {
    float2 a = Ag[i];
    sAre[(i >> 7) * RS + (i & 127)] = a.x;
    sAim[(i >> 7) * RS + (i & 127)] = a.y;
  }
  // decode this thread's canonical slot-pair blocks (i<=j), fixed all rounds
  int nb = (tid >= 480) ? 5 : 4;
  int bi_[5], bj_[5];
#pragma unroll
  for (int k = 0; k < 4; ++k) {
    int e = tid + 512 * k;
    int i = 0;
    while (i < 63 && (64 * (i + 1) - ((i + 1) * i) / 2) <= e) ++i;
    bi_[k] = i;
    bj_[k] = i + (e - (64 * i - (i * (i - 1)) / 2));
  }
  if (nb == 5) {
    int e = 2048 + (tid - 480);
    int i = 0;
    while (i < 63 && (64 * (i + 1) - ((i + 1) * i) / 2) <= e) ++i;
    bi_[4] = i;
    bj_[4] = i + (e - (64 * i - (i * (i - 1)) / 2));
  }
  __syncthreads();
  for (int r0 = 0; r0 < 127; ++r0) {
    int r = (sweep & 1) ? (126 - r0) : r0;
    if (tid < 64) {
      int p = pair_p(tid, r), q = pair_q(tid, r);
      float app = sAre[p * RS + p], aqq = sAre[q * RS + q];
      float2 g = ldc(sAre, sAim, p, q);
      float ag2 = g.x * g.x + g.y * g.y;
      float cc = 1.0f, br = 0.0f, bi = 0.0f;
      if (ag2 > 1e-24f) {
        float ag = sqrtf(ag2);
        float ta = (aqq - app) / (2.0f * ag);
        float tt = -copysignf(1.0f, ta) / (fabsf(ta) + sqrtf(1.0f + ta * ta));
        cc = 1.0f / sqrtf(1.0f + tt * tt);
        float tcag = tt * cc / ag;
        br = g.x * tcag; bi = g.y * tcag;
      }
      sprm[tid] = make_float4(cc, br, bi, __int_as_float(p | (q << 8)));
      Pg[r0 * 64 + tid] = make_float2(br, bi);
    }
    __syncthreads();   // params visible; all pre-round A reads done (WAR)
    for (int k = 0; k < nb; ++k) {
      float4 Pi = sprm[bi_[k]], Pj = sprm[bj_[k]];
      int pqi = __float_as_int(Pi.w), pqj = __float_as_int(Pj.w);
      int pi_ = pqi & 255, qi_ = pqi >> 8;
      int pj_ = pqj & 255, qj_ = pqj >> 8;
      float ci = Pi.x, bri = Pi.y, bii = Pi.z;
      float cj = Pj.x, brj = Pj.y, bij = Pj.z;
      float2 B00 = ldc(sAre, sAim, pi_, pj_);
      float2 B01 = ldc(sAre, sAim, pi_, qj_);
      float2 B10 = ldc(sAre, sAim, qi_, pj_);
      float2 B11 = ldc(sAre, sAim, qi_, qj_);
      // left: T = L_i * B
      float t00r = ci * B00.x + (bri * B10.x - bii * B10.y);
      float t00i = ci * B00.y + (bri * B10.y + bii * B10.x);
      float t01r = ci * B01.x + (bri * B11.x - bii * B11.y);
      float t01i = ci * B01.y + (bri * B11.y + bii * B11.x);
      float t10r = ci * B10.x - (bri * B00.x + bii * B00.y);
      float t10i = ci * B10.y - (bri * B00.y - bii * B00.x);
      float t11r = ci * B11.x - (bri * B01.x + bii * B01.y);
      float t11i = ci * B11.y - (bri * B01.y - bii * B01.x);
      // right: C = T * R_j
      stc(sAre, sAim, pi_, pj_,
          cj * t00r + (brj * t01r + bij * t01i),
          cj * t00i + (brj * t01i - bij * t01r));
      stc(sAre, sAim, pi_, qj_,
          cj * t01r - (brj * t00r - bij * t00i),
          cj * t01i - (brj * t00i + bij * t00r));
      stc(sAre, sAim, qi_, pj_,
          cj * t10r + (brj * t11r + bij * t11i),
          cj * t10i + (brj * t11i - bij * t11r));
      stc(sAre, sAim, qi_, qj_,
          cj * t11r - (brj * t10r - bij * t10i),
          cj * t11i - (brj * t10i + bij * t10r));
    }
    __syncthreads();   // RAW: writes visible before next round's reads
  }
  for (int i = tid; i < NSQ; i += 512) {
    Ag[i] = make_float2(sAre[(i >> 7) * RS + (i & 127)],
                        sAim[(i >> 7) * RS + (i & 127)]);
  }
  if (last && tid < NDIM) {   // fused rankd (diag is canonical)
    float wj = sAre[tid * RS + tid];
    int rank = 0;
    for (int k2 = 0; k2 < NDIM; ++k2) {
      float wk = sAre[k2 * RS + k2];
      rank += (wk < wj) || (wk == wj && k2 < tid);
    }
    double mv = minv[(it * BATCH + b) * NDIM + rank];
    double v = (double)wj + mv;
    if (v < 0.0) v = 0.0;
    d1[b * NDIM + tid] = v;
    d2[b * NDIM + tid] = v - (double)wj;
  }
}

// Final replay of the last sweep (before update_kernel).
__global__ __launch_bounds__(512) void replay_kernel(
    float2* __restrict__ U, const float2* __restrict__ params, int sweep) {
  extern __shared__ float smem[];
  replay_body(smem, U, params, blockIdx.x, sweep);
}

// Theta = V diag(d1) V^H ; Lamda = (1-e/r) Lamda + e * V diag(d2) V^H.
__global__ __launch_bounds__(256) void update_kernel(
    const float2* U, const double* d1, const double* d2,
    const float* rho, const float* eta, int it,
    double2* Theta, double2* Lamda) {
  __shared__ float ViRe[32][33], ViIm[32][33];
  __shared__ float VkRe[32][33], VkIm[32][33];
  __shared__ double s1[32], s2[32];
  int blk = blockIdx.x;
  int b = blk >> 4, tile = blk & 15, ti = tile >> 2, tk = tile & 3;
  int tid = threadIdx.x;
  int lk = tid & 31, lig = tid >> 5;
  double r = (double)rho[it], e = (double)eta[it];
  double a1x[4] = {0, 0, 0, 0}, a1y[4] = {0, 0, 0, 0};
  double a2x[4] = {0, 0, 0, 0}, a2y[4] = {0, 0, 0, 0};
  const float2* Ub = U + (size_t)b * NSQ;
  for (int jc = 0; jc < 4; ++jc) {
    for (int e2 = tid; e2 < 1024; e2 += 256) {
      int rr = e2 & 31, cc2 = e2 >> 5;
      float2 v1 = Ub[(jc * 32 + cc2) * NDIM + ti * 32 + rr];
      ViRe[rr][cc2] = v1.x; ViIm[rr][cc2] = v1.y;
      float2 v2 = Ub[(jc * 32 + cc2) * NDIM + tk * 32 + rr];
      VkRe[rr][cc2] = v2.x; VkIm[rr][cc2] = v2.y;
    }
    if (tid < 32) {
      s1[tid] = d1[b * NDIM + jc * 32 + tid];
      s2[tid] = d2[b * NDIM + jc * 32 + tid];
    }
    __syncthreads();
#pragma unroll
    for (int uo = 0; uo < 4; ++uo) {
      int li = lig + uo * 8;
      double ax = a1x[uo], ay = a1y[uo], bx = a2x[uo], by = a2y[uo];
      for (int jj = 0; jj < 32; ++jj) {
        float var = ViRe[li][jj], vai = ViIm[li][jj];
        float vbr = VkRe[lk][jj], vbi = VkIm[lk][jj];
        double pr = (double)(var * vbr + vai * vbi);
        double pi = (double)(vai * vbr - var * vbi);
        ax += s1[jj] * pr; ay += s1[jj] * pi;
        bx += s2[jj] * pr; by += s2[jj] * pi;
      }
      a1x[uo] = ax; a1y[uo] = ay; a2x[uo] = bx; a2y[uo] = by;
    }
    __syncthreads();
  }
  double lf = 1.0 - e / r;
#pragma unroll
  for (int uo = 0; uo < 4; ++uo) {
    int gi = ti * 32 + lig + uo * 8, gk = tk * 32 + lk;
    size_t idx = (size_t)b * NSQ + gi * NDIM + gk;
    Theta[idx] = make_double2(a1x[uo], a1y[uo]);
    double2 Lold = Lamda[idx];
    Lamda[idx] = make_double2(lf * Lold.x + e * a2x[uo], lf * Lold.y + e * a2y[uo]);
  }
}

// OUTPUT (float32 real parts): T[i][j] = u[|i-j|].re ; uvec.re = u.re
__global__ void writeout_kernel(const double2* u, float* out) {
  int tid = blockIdx.x * 256 + threadIdx.x;
  if (tid >= OUT_ELEMS) return;
  double re;
  if (tid < BATCH * MDIM * MDIM) {
    int b = tid >> 12, rem = tid & 4095, i = rem >> 6, j = rem & 63;
    int d = j - i;
    re = u[b * MDIM + (d >= 0 ? d : -d)].x;
  } else {
    int k2 = tid - BATCH * MDIM * MDIM;
    int b = k2 >> 6, kk = k2 & 63;
    re = u[b * MDIM + kk].x;
  }
  out[tid] = (float)re;
}

// ------------------------------- launch ------------------------------------
extern "C" void kernel_launch(void* const* d_in, const int* in_sizes, int n_in,
                              void* d_out, int out_size, void* d_ws, size_t ws_size,
                              hipStream_t stream) {
  const float* Yre = (const float*)d_in[0];
  const float* Yim = (const float*)d_in[1];
  const float* rho = (const float*)d_in[2];
  const float* tau = (const float*)d_in[3];
  const float* eta = (const float*)d_in[4];
  float* out = (float*)d_out;

  char* ws = (char*)d_ws;
  size_t off = 0;
  auto take = [&](size_t bytes) -> char* {
    char* p = ws + off;
    off += (bytes + 255) & ~(size_t)255;
    return p;
  };
  double2* u     = (double2*)take((size_t)BATCH * MDIM * sizeof(double2));
  double*  minv  = (double*)take((size_t)KITER * BATCH * NDIM * sizeof(double));
  double*  d1    = (double*)take((size_t)BATCH * NDIM * sizeof(double));
  double*  d2    = (double*)take((size_t)BATCH * NDIM * sizeof(double));
  double2* Lamda = (double2*)take((size_t)BATCH * NSQ * sizeof(double2));  // 16.8 MB
  double2* Theta = (double2*)take((size_t)BATCH * NSQ * sizeof(double2));  // 16.8 MB
  float2*  A32   = (float2*)take((size_t)BATCH * NSQ * sizeof(float2));    //  8.4 MB
  float2*  U32   = (float2*)take((size_t)BATCH * NSQ * sizeof(float2));    //  8.4 MB
  float2*  prm0  = (float2*)take((size_t)BATCH * 127 * 64 * sizeof(float2)); // 4.2 MB
  float2*  prm1  = (float2*)take((size_t)BATCH * 127 * 64 * sizeof(float2)); // 4.2 MB
  float2*  prmB[2] = {prm0, prm1};
  (void)in_sizes; (void)n_in; (void)ws_size; (void)out_size;  // ~59.7 MB total

  hipFuncSetAttribute((const void*)combined_kernel,
                      hipFuncAttributeMaxDynamicSharedMemorySize, JAC_LDS_BYTES);
  hipFuncSetAttribute((const void*)replay_kernel,
                      hipFuncAttributeMaxDynamicSharedMemorySize, JAC_LDS_BYTES);

  zero_kernel<<<2048, 256, 0, stream>>>((double*)Theta, (size_t)BATCH * NSQ * 2);
  zero_kernel<<<2048, 256, 0, stream>>>((double*)Lamda, (size_t)BATCH * NSQ * 2);
  prng_kernel<<<(KITER * BATCH * NDIM + 255) / 256, 256, 0, stream>>>(minv);

  for (int it = 0; it < KITER - 1; ++it) {
    compute_u_kernel<<<16, 256, 0, stream>>>(Theta, Lamda, rho, tau, it, u);
    assemble_kernel<<<BATCH * NSQ / 256, 256, 0, stream>>>(Theta, Lamda, u, Yre, Yim,
                                                           rho, tau, it, A32, U32);
    for (int s = 0; s < SWEEPS; ++s) {
      combined_kernel<<<BATCH + 2 * BATCH, 512, JAC_LDS_BYTES, stream>>>(
          A32, U32, prmB[s & 1], prmB[(s + 1) & 1], minv, it, s,
          (s == SWEEPS - 1) ? 1 : 0, d1, d2);
    }
    replay_kernel<<<2 * BATCH, 512, JAC_LDS_BYTES, stream>>>(
        U32, prmB[(SWEEPS - 1) & 1], SWEEPS - 1);
    update_kernel<<<BATCH * 16, 256, 0, stream>>>(U32, d1, d2, rho, eta, it, Theta, Lamda);
  }
  compute_u_kernel<<<16, 256, 0, stream>>>(Theta, Lamda, rho, tau, KITER - 1, u);
  writeout_kernel<<<(OUT_ELEMS + 255) / 256, 256, 0, stream>>>(u, out);
}